// Round 7
// baseline (155.555 us; speedup 1.0000x reference)
//
#include <hip/hip_runtime.h>
#include <hip/hip_bf16.h>

#define S_LEN 2048
#define DH 64
#define QBLK 128
#define KVBLK 64
#define LDPK 72   // K rows: 144B (16B-aligned)
#define LDPV 68   // V^T rows: 136B (8B-aligned)

typedef __attribute__((ext_vector_type(4))) float f32x4;
typedef __attribute__((ext_vector_type(8))) short short8v;
typedef __attribute__((ext_vector_type(4))) unsigned uint4v;
typedef __attribute__((ext_vector_type(2))) unsigned uint2v;

__device__ __forceinline__ unsigned cvt_pk(float a, float b) {
    unsigned r;
    asm("v_cvt_pk_bf16_f32 %0, %1, %2" : "=v"(r) : "v"(a), "v"(b));
    return r;
}

__global__ __launch_bounds__(256) void fa_fwd_kernel(
    const float* __restrict__ Q, const float* __restrict__ K,
    const float* __restrict__ V, float* __restrict__ O)
{
    const int tid  = threadIdx.x;
    const int lane = tid & 63;
    const int w    = tid >> 6;          // 0..3 waves, each owns 32 q-rows (rt=2)
    const int bh   = blockIdx.x & 63;
    const int j    = blockIdx.x >> 6;   // 0..15
    // balanced-cohort LPT: round-robin groups of 4 qb values each sum to 30
    const int qb   = (j < 4) ? (15 - j) : (j < 8) ? (j + 4)
                   : (j < 12) ? (j - 4) : (15 - j);

    const size_t base = (size_t)bh * S_LEN * DH;
    const float* Qg = Q + base;
    const float* Kg = K + base;
    const float* Vg = V + base;
    float*       Og = O + base;

    __shared__ __align__(16) short K_lds[2][KVBLK][LDPK];   // [buf][kv][d]
    __shared__ __align__(16) short V_lds[2][DH][LDPV];      // [buf][d][kv]

    const int lr = lane & 15;
    const int lg = lane >> 4;
    // staging decomposition (256 threads cover the 64x64 tile once)
    const int kr = tid >> 2;            // K row 0..63
    const int dc = (tid & 3) * 16;      // K col 0,16,32,48
    const int vd = tid & 63;            // V col (d)
    const int vg = tid >> 6;            // V row-group 0..3

    unsigned kpfu[8], vpf[8];

    auto prefetch = [&](int kvb) {
        const float* kp = Kg + (size_t)(kvb + kr) * DH + dc;
        f32x4 a = *(const f32x4*)kp;
        f32x4 b = *(const f32x4*)(kp + 4);
        f32x4 c = *(const f32x4*)(kp + 8);
        f32x4 d = *(const f32x4*)(kp + 12);
        kpfu[0] = cvt_pk(a[0], a[1]); kpfu[1] = cvt_pk(a[2], a[3]);
        kpfu[2] = cvt_pk(b[0], b[1]); kpfu[3] = cvt_pk(b[2], b[3]);
        kpfu[4] = cvt_pk(c[0], c[1]); kpfu[5] = cvt_pk(c[2], c[3]);
        kpfu[6] = cvt_pk(d[0], d[1]); kpfu[7] = cvt_pk(d[2], d[3]);
        #pragma unroll
        for (int i = 0; i < 8; ++i) {
            int kv = vg * 16 + i * 2;
            float x = Vg[(size_t)(kvb + kv) * DH + vd];
            float y = Vg[(size_t)(kvb + kv + 1) * DH + vd];
            vpf[i] = cvt_pk(x, y);
        }
    };

    auto stage = [&](int b) {
        uint4v u0 = {kpfu[0], kpfu[1], kpfu[2], kpfu[3]};
        uint4v u1 = {kpfu[4], kpfu[5], kpfu[6], kpfu[7]};
        *(uint4v*)&K_lds[b][kr][dc]     = u0;   // ds_write_b128
        *(uint4v*)&K_lds[b][kr][dc + 8] = u1;
        #pragma unroll
        for (int i = 0; i < 8; ++i) {
            int kv = vg * 16 + i * 2;
            *(unsigned*)((char*)&V_lds[b][0][0] + vd * (LDPV * 2) + kv * 2) = vpf[i];
        }
    };

    const float qscale = 0.125f * 1.44269504088896340736f;
    const int q0 = qb * QBLK + w * 32;       // this wave's 32 q-rows
    const int kv_end = (qb + 1) * QBLK;

    // ---- Q fragments (scale + log2e folded) ----
    short8v qfrag[2][2];
    #pragma unroll
    for (int rt = 0; rt < 2; ++rt) {
        #pragma unroll
        for (int kf = 0; kf < 2; ++kf) {
            const float* qp = Qg + (size_t)(q0 + rt * 16 + lr) * DH + kf * 32 + lg * 8;
            f32x4 a = *(const f32x4*)qp;
            f32x4 b = *(const f32x4*)(qp + 4);
            uint4v u;
            u[0] = cvt_pk(a[0] * qscale, a[1] * qscale);
            u[1] = cvt_pk(a[2] * qscale, a[3] * qscale);
            u[2] = cvt_pk(b[0] * qscale, b[1] * qscale);
            u[3] = cvt_pk(b[2] * qscale, b[3] * qscale);
            qfrag[rt][kf] = __builtin_bit_cast(short8v, u);
        }
    }

    f32x4 o_acc[2][4];
    float m_run[2], l_run[2];
    #pragma unroll
    for (int rt = 0; rt < 2; ++rt) {
        #pragma unroll
        for (int i = 0; i < 4; ++i)
            o_acc[rt][i] = (f32x4){0.f, 0.f, 0.f, 0.f};
        m_run[rt] = -1e30f;
        l_run[rt] = 0.f;
    }

    prefetch(0);
    stage(0);
    int cur = 0;
    __syncthreads();

    #pragma unroll 1
    for (int kvb = 0; kvb < kv_end; kvb += KVBLK) {
        int nkv = kvb + KVBLK;
        const bool have = nkv < kv_end;
        if (have) prefetch(nkv);    // global->reg, lands under compute

        if (kvb <= q0) {            // skip fully-masked diagonal iterations
            const short (*Kc)[LDPK] = K_lds[cur];
            const char* Vc = (const char*)&V_lds[cur][0][0];

            // ---- swapped QK^T: lane holds q=lr, kv=16kt+4lg+r ----
            f32x4 s_acc[2][4];
            #pragma unroll
            for (int rt = 0; rt < 2; ++rt)
                #pragma unroll
                for (int kt = 0; kt < 4; ++kt)
                    s_acc[rt][kt] = (f32x4){0.f, 0.f, 0.f, 0.f};

            __builtin_amdgcn_s_setprio(1);
            #pragma unroll
            for (int kt = 0; kt < 4; ++kt) {
                short8v kf0 = *(const short8v*)&Kc[kt * 16 + lr][lg * 8];
                short8v kf1 = *(const short8v*)&Kc[kt * 16 + lr][32 + lg * 8];
                #pragma unroll
                for (int rt = 0; rt < 2; ++rt) {
                    s_acc[rt][kt] = __builtin_amdgcn_mfma_f32_16x16x32_bf16(
                        kf0, qfrag[rt][0], s_acc[rt][kt], 0, 0, 0);
                    s_acc[rt][kt] = __builtin_amdgcn_mfma_f32_16x16x32_bf16(
                        kf1, qfrag[rt][1], s_acc[rt][kt], 0, 0, 0);
                }
            }
            __builtin_amdgcn_s_setprio(0);

            // ---- mask (diagonal tiles only) ----
            if (kvb + KVBLK - 1 > q0) {
                #pragma unroll
                for (int rt = 0; rt < 2; ++rt) {
                    const int qrow = q0 + rt * 16 + lr;
                    #pragma unroll
                    for (int kt = 0; kt < 4; ++kt)
                        #pragma unroll
                        for (int r = 0; r < 4; ++r) {
                            int kvv = kvb + kt * 16 + lg * 4 + r;
                            if (kvv > qrow) s_acc[rt][kt][r] = -1e30f;
                        }
                }
            }

            // ---- online softmax, defer-max: in-lane max check only ----
            float tl[2];
            #pragma unroll
            for (int rt = 0; rt < 2; ++rt) {
                tl[rt] = -1e30f;
                #pragma unroll
                for (int kt = 0; kt < 4; ++kt)
                    #pragma unroll
                    for (int r = 0; r < 4; ++r)
                        tl[rt] = fmaxf(tl[rt], s_acc[rt][kt][r]);
            }
            if (!__all(tl[0] <= m_run[0] + 8.0f && tl[1] <= m_run[1] + 8.0f)) {
                #pragma unroll
                for (int rt = 0; rt < 2; ++rt) {
                    float tmax = tl[rt];
                    tmax = fmaxf(tmax, __shfl_xor(tmax, 16));
                    tmax = fmaxf(tmax, __shfl_xor(tmax, 32));
                    float mnew = fmaxf(m_run[rt], tmax);
                    float corr = __builtin_amdgcn_exp2f(m_run[rt] - mnew);
                    m_run[rt] = mnew;
                    l_run[rt] *= corr;
                    #pragma unroll
                    for (int r = 0; r < 4; ++r) {
                        float c = __shfl(corr, 4 * lg + r);
                        #pragma unroll
                        for (int dt = 0; dt < 4; ++dt)
                            o_acc[rt][dt][r] *= c;
                    }
                }
            }

            short8v pa[2][2];
            #pragma unroll
            for (int rt = 0; rt < 2; ++rt) {
                float rsum = 0.f;
                #pragma unroll
                for (int kt = 0; kt < 4; ++kt)
                    #pragma unroll
                    for (int r = 0; r < 4; ++r) {
                        float pe = __builtin_amdgcn_exp2f(s_acc[rt][kt][r] - m_run[rt]);
                        s_acc[rt][kt][r] = pe;
                        rsum += pe;
                    }
                rsum += __shfl_xor(rsum, 16);
                rsum += __shfl_xor(rsum, 32);
                l_run[rt] += rsum;

                #pragma unroll
                for (int kf = 0; kf < 2; ++kf) {
                    uint4v u;
                    u[0] = cvt_pk(s_acc[rt][2 * kf][0],     s_acc[rt][2 * kf][1]);
                    u[1] = cvt_pk(s_acc[rt][2 * kf][2],     s_acc[rt][2 * kf][3]);
                    u[2] = cvt_pk(s_acc[rt][2 * kf + 1][0], s_acc[rt][2 * kf + 1][1]);
                    u[3] = cvt_pk(s_acc[rt][2 * kf + 1][2], s_acc[rt][2 * kf + 1][3]);
                    pa[rt][kf] = __builtin_bit_cast(short8v, u);
                }
            }

            // ---- PV: V-frags shared across rt ----
            __builtin_amdgcn_s_setprio(1);
            #pragma unroll
            for (int dt = 0; dt < 4; ++dt) {
                const char* vrow = Vc + (dt * 16 + lr) * (LDPV * 2);
                #pragma unroll
                for (int kf = 0; kf < 2; ++kf) {
                    uint2v lo = *(const uint2v*)(vrow + (kf * 32 + 4 * lg) * 2);
                    uint2v hi = *(const uint2v*)(vrow + (kf * 32 + 16 + 4 * lg) * 2);
                    uint4v u = {lo[0], lo[1], hi[0], hi[1]};
                    short8v vv = __builtin_bit_cast(short8v, u);
                    #pragma unroll
                    for (int rt = 0; rt < 2; ++rt)
                        o_acc[rt][dt] = __builtin_amdgcn_mfma_f32_16x16x32_bf16(
                            pa[rt][kf], vv, o_acc[rt][dt], 0, 0, 0);
                }
            }
            __builtin_amdgcn_s_setprio(0);
        }

        if (have) {
            stage(cur ^ 1);
            __syncthreads();
        }
        cur ^= 1;
    }

    // ---- epilogue ----
    #pragma unroll
    for (int rt = 0; rt < 2; ++rt) {
        #pragma unroll
        for (int r = 0; r < 4; ++r) {
            float ls = __shfl(l_run[rt], 4 * lg + r);
            float inv = 1.0f / ls;
            int qrow = q0 + rt * 16 + lg * 4 + r;
            float* op = Og + (size_t)qrow * DH + lr;
            #pragma unroll
            for (int dt = 0; dt < 4; ++dt)
                op[dt * 16] = o_acc[rt][dt][r] * inv;
        }
    }
}

extern "C" void kernel_launch(void* const* d_in, const int* in_sizes, int n_in,
                              void* d_out, int out_size, void* d_ws, size_t ws_size,
                              hipStream_t stream) {
    const float* q = (const float*)d_in[0];
    const float* k = (const float*)d_in[1];
    const float* v = (const float*)d_in[2];
    float* out = (float*)d_out;
    // 1024 blocks x 256 threads: 64 (b,h) x 16 q-tiles, balanced-cohort qb order
    fa_fwd_kernel<<<dim3(1024), dim3(256), 0, stream>>>(q, k, v, out);
}

// Round 8
// 89.551 us; speedup vs baseline: 1.7371x; 1.7371x over previous
//
#include <hip/hip_runtime.h>
#include <hip/hip_bf16.h>

#define S_LEN 2048
#define DH 64
#define QBLK 128
#define KVBLK 64
#define LDPK 72   // K rows: 144B (16B-aligned)
#define LDPV 68   // V^T rows: 136B (8B-aligned)

typedef __attribute__((ext_vector_type(4))) float f32x4;
typedef __attribute__((ext_vector_type(8))) short short8v;
typedef __attribute__((ext_vector_type(4))) unsigned uint4v;
typedef __attribute__((ext_vector_type(2))) unsigned uint2v;

__device__ __forceinline__ unsigned cvt_pk(float a, float b) {
    unsigned r;
    asm("v_cvt_pk_bf16_f32 %0, %1, %2" : "=v"(r) : "v"(a), "v"(b));
    return r;
}

__global__ __launch_bounds__(256) void fa_fwd_kernel(
    const float* __restrict__ Q, const float* __restrict__ K,
    const float* __restrict__ V, float* __restrict__ O)
{
    const int tid  = threadIdx.x;
    const int lane = tid & 63;
    const int w    = tid >> 6;          // 0..3 waves, each owns 32 q-rows (rt=2)
    const int bh   = blockIdx.x & 63;   // same-bh blocks 64 apart -> same XCD
    const int p    = blockIdx.x >> 6;   // 0..7; sequential pair {15-p, p}: 34 iters uniform

    const size_t base = (size_t)bh * S_LEN * DH;
    const float* Qg = Q + base;
    const float* Kg = K + base;
    const float* Vg = V + base;
    float*       Og = O + base;

    __shared__ __align__(16) short K_lds[2][KVBLK][LDPK];   // [buf][kv][d]
    __shared__ __align__(16) short V_lds[2][DH][LDPV];      // [buf][d][kv]

    const int lr = lane & 15;
    const int lg = lane >> 4;
    // staging decomposition (256 threads cover the 64x64 tile once)
    const int kr = tid >> 2;            // K row 0..63
    const int dc = (tid & 3) * 16;      // K col 0,16,32,48
    const int vd = tid & 63;            // V col (d)
    const int vg = tid >> 6;            // V row-group 0..3

    unsigned kpfu[8], vpf[8];

    auto prefetch = [&](int kvb) {
        const float* kp = Kg + (size_t)(kvb + kr) * DH + dc;
        f32x4 a = *(const f32x4*)kp;
        f32x4 b = *(const f32x4*)(kp + 4);
        f32x4 c = *(const f32x4*)(kp + 8);
        f32x4 d = *(const f32x4*)(kp + 12);
        kpfu[0] = cvt_pk(a[0], a[1]); kpfu[1] = cvt_pk(a[2], a[3]);
        kpfu[2] = cvt_pk(b[0], b[1]); kpfu[3] = cvt_pk(b[2], b[3]);
        kpfu[4] = cvt_pk(c[0], c[1]); kpfu[5] = cvt_pk(c[2], c[3]);
        kpfu[6] = cvt_pk(d[0], d[1]); kpfu[7] = cvt_pk(d[2], d[3]);
        #pragma unroll
        for (int i = 0; i < 8; ++i) {
            int kv = vg * 16 + i * 2;
            float x = Vg[(size_t)(kvb + kv) * DH + vd];
            float y = Vg[(size_t)(kvb + kv + 1) * DH + vd];
            vpf[i] = cvt_pk(x, y);
        }
    };

    auto stage = [&](int b) {
        uint4v u0 = {kpfu[0], kpfu[1], kpfu[2], kpfu[3]};
        uint4v u1 = {kpfu[4], kpfu[5], kpfu[6], kpfu[7]};
        *(uint4v*)&K_lds[b][kr][dc]     = u0;   // ds_write_b128
        *(uint4v*)&K_lds[b][kr][dc + 8] = u1;
        #pragma unroll
        for (int i = 0; i < 8; ++i) {
            int kv = vg * 16 + i * 2;
            *(unsigned*)((char*)&V_lds[b][0][0] + vd * (LDPV * 2) + kv * 2) = vpf[i];
        }
    };

    const float qscale = 0.125f * 1.44269504088896340736f;

    prefetch(0);
    stage(0);
    int cur = 0;
    __syncthreads();

    #pragma unroll 1
    for (int t = 0; t < 2; ++t) {
        const int qb = (t == 0) ? (15 - p) : p;   // heavy tile first
        const int q0 = qb * QBLK + w * 32;        // this wave's 32 q-rows
        const int kv_end = (qb + 1) * QBLK;

        // ---- Q fragments (scale + log2e folded) ----
        short8v qfrag[2][2];
        #pragma unroll
        for (int rt = 0; rt < 2; ++rt) {
            #pragma unroll
            for (int kf = 0; kf < 2; ++kf) {
                const float* qp = Qg + (size_t)(q0 + rt * 16 + lr) * DH + kf * 32 + lg * 8;
                f32x4 a = *(const f32x4*)qp;
                f32x4 b = *(const f32x4*)(qp + 4);
                uint4v u;
                u[0] = cvt_pk(a[0] * qscale, a[1] * qscale);
                u[1] = cvt_pk(a[2] * qscale, a[3] * qscale);
                u[2] = cvt_pk(b[0] * qscale, b[1] * qscale);
                u[3] = cvt_pk(b[2] * qscale, b[3] * qscale);
                qfrag[rt][kf] = __builtin_bit_cast(short8v, u);
            }
        }

        f32x4 o_acc[2][4];
        float m_run[2], l_run[2];
        #pragma unroll
        for (int rt = 0; rt < 2; ++rt) {
            #pragma unroll
            for (int i = 0; i < 4; ++i)
                o_acc[rt][i] = (f32x4){0.f, 0.f, 0.f, 0.f};
            m_run[rt] = -1e30f;
            l_run[rt] = 0.f;
        }

        #pragma unroll 1
        for (int kvb = 0; kvb < kv_end; kvb += KVBLK) {
            // next tile to prefetch (crosses into second q-tile seamlessly)
            int nkv = kvb + KVBLK;
            bool have = true;
            if (nkv >= kv_end) { if (t == 0) nkv = 0; else have = false; }
            if (have) prefetch(nkv);   // global->reg, lands under compute

            if (kvb <= q0) {           // skip fully-masked diagonal iterations
                const short (*Kc)[LDPK] = K_lds[cur];
                const char* Vc = (const char*)&V_lds[cur][0][0];

                // ---- swapped QK^T: lane holds q=lr, kv=16kt+4lg+r ----
                f32x4 s_acc[2][4];
                #pragma unroll
                for (int rt = 0; rt < 2; ++rt)
                    #pragma unroll
                    for (int kt = 0; kt < 4; ++kt)
                        s_acc[rt][kt] = (f32x4){0.f, 0.f, 0.f, 0.f};

                __builtin_amdgcn_s_setprio(1);
                #pragma unroll
                for (int kt = 0; kt < 4; ++kt) {
                    short8v kf0 = *(const short8v*)&Kc[kt * 16 + lr][lg * 8];
                    short8v kf1 = *(const short8v*)&Kc[kt * 16 + lr][32 + lg * 8];
                    #pragma unroll
                    for (int rt = 0; rt < 2; ++rt) {
                        s_acc[rt][kt] = __builtin_amdgcn_mfma_f32_16x16x32_bf16(
                            kf0, qfrag[rt][0], s_acc[rt][kt], 0, 0, 0);
                        s_acc[rt][kt] = __builtin_amdgcn_mfma_f32_16x16x32_bf16(
                            kf1, qfrag[rt][1], s_acc[rt][kt], 0, 0, 0);
                    }
                }
                __builtin_amdgcn_s_setprio(0);

                // ---- mask (diagonal tiles only) ----
                if (kvb + KVBLK - 1 > q0) {
                    #pragma unroll
                    for (int rt = 0; rt < 2; ++rt) {
                        const int qrow = q0 + rt * 16 + lr;
                        #pragma unroll
                        for (int kt = 0; kt < 4; ++kt)
                            #pragma unroll
                            for (int r = 0; r < 4; ++r) {
                                int kvv = kvb + kt * 16 + lg * 4 + r;
                                if (kvv > qrow) s_acc[rt][kt][r] = -1e30f;
                            }
                    }
                }

                // ---- online softmax, defer-max: in-lane max check first ----
                float tl[2];
                #pragma unroll
                for (int rt = 0; rt < 2; ++rt) {
                    tl[rt] = -1e30f;
                    #pragma unroll
                    for (int kt = 0; kt < 4; ++kt)
                        #pragma unroll
                        for (int r = 0; r < 4; ++r)
                            tl[rt] = fmaxf(tl[rt], s_acc[rt][kt][r]);
                }
                if (!__all(tl[0] <= m_run[0] + 8.0f && tl[1] <= m_run[1] + 8.0f)) {
                    #pragma unroll
                    for (int rt = 0; rt < 2; ++rt) {
                        float tmax = tl[rt];
                        tmax = fmaxf(tmax, __shfl_xor(tmax, 16));
                        tmax = fmaxf(tmax, __shfl_xor(tmax, 32));
                        float mnew = fmaxf(m_run[rt], tmax);
                        float corr = __builtin_amdgcn_exp2f(m_run[rt] - mnew);
                        m_run[rt] = mnew;
                        l_run[rt] *= corr;
                        #pragma unroll
                        for (int r = 0; r < 4; ++r) {
                            float c = __shfl(corr, 4 * lg + r);
                            #pragma unroll
                            for (int dt = 0; dt < 4; ++dt)
                                o_acc[rt][dt][r] *= c;
                        }
                    }
                }

                short8v pa[2][2];
                #pragma unroll
                for (int rt = 0; rt < 2; ++rt) {
                    float rsum = 0.f;
                    #pragma unroll
                    for (int kt = 0; kt < 4; ++kt)
                        #pragma unroll
                        for (int r = 0; r < 4; ++r) {
                            float pe = __builtin_amdgcn_exp2f(s_acc[rt][kt][r] - m_run[rt]);
                            s_acc[rt][kt][r] = pe;
                            rsum += pe;
                        }
                    rsum += __shfl_xor(rsum, 16);
                    rsum += __shfl_xor(rsum, 32);
                    l_run[rt] += rsum;

                    #pragma unroll
                    for (int kf = 0; kf < 2; ++kf) {
                        uint4v u;
                        u[0] = cvt_pk(s_acc[rt][2 * kf][0],     s_acc[rt][2 * kf][1]);
                        u[1] = cvt_pk(s_acc[rt][2 * kf][2],     s_acc[rt][2 * kf][3]);
                        u[2] = cvt_pk(s_acc[rt][2 * kf + 1][0], s_acc[rt][2 * kf + 1][1]);
                        u[3] = cvt_pk(s_acc[rt][2 * kf + 1][2], s_acc[rt][2 * kf + 1][3]);
                        pa[rt][kf] = __builtin_bit_cast(short8v, u);
                    }
                }

                // ---- PV: V-frags shared across rt ----
                __builtin_amdgcn_s_setprio(1);
                #pragma unroll
                for (int dt = 0; dt < 4; ++dt) {
                    const char* vrow = Vc + (dt * 16 + lr) * (LDPV * 2);
                    #pragma unroll
                    for (int kf = 0; kf < 2; ++kf) {
                        uint2v lo = *(const uint2v*)(vrow + (kf * 32 + 4 * lg) * 2);
                        uint2v hi = *(const uint2v*)(vrow + (kf * 32 + 16 + 4 * lg) * 2);
                        uint4v u = {lo[0], lo[1], hi[0], hi[1]};
                        short8v vv = __builtin_bit_cast(short8v, u);
                        #pragma unroll
                        for (int rt = 0; rt < 2; ++rt)
                            o_acc[rt][dt] = __builtin_amdgcn_mfma_f32_16x16x32_bf16(
                                pa[rt][kf], vv, o_acc[rt][dt], 0, 0, 0);
                    }
                }
                __builtin_amdgcn_s_setprio(0);
            }

            // ---- stage next tile into the other buffer; single barrier ----
            if (have) {
                stage(cur ^ 1);
                __syncthreads();
            }
            cur ^= 1;
        }

        // ---- epilogue for this q-tile ----
        #pragma unroll
        for (int rt = 0; rt < 2; ++rt) {
            #pragma unroll
            for (int r = 0; r < 4; ++r) {
                float ls = __shfl(l_run[rt], 4 * lg + r);
                float inv = 1.0f / ls;
                int qrow = q0 + rt * 16 + lg * 4 + r;
                float* op = Og + (size_t)qrow * DH + lr;
                #pragma unroll
                for (int dt = 0; dt < 4; ++dt)
                    op[dt * 16] = o_acc[rt][dt][r] * inv;
            }
        }
    }
}

extern "C" void kernel_launch(void* const* d_in, const int* in_sizes, int n_in,
                              void* d_out, int out_size, void* d_ws, size_t ws_size,
                              hipStream_t stream) {
    const float* q = (const float*)d_in[0];
    const float* k = (const float*)d_in[1];
    const float* v = (const float*)d_in[2];
    float* out = (float*)d_out;
    // 512 uniform blocks x 256 threads: 64 (b,h) x 8 q-tile pairs {15-p, p}, rt=2
    fa_fwd_kernel<<<dim3(512), dim3(256), 0, stream>>>(q, k, v, out);
}

// Round 9
// 86.959 us; speedup vs baseline: 1.7888x; 1.0298x over previous
//
#include <hip/hip_runtime.h>
#include <hip/hip_bf16.h>

#define S_LEN 2048
#define DH 64
#define QBLK 128
#define KVBLK 64
#define LDPK 72   // K rows: 144B (16B-aligned)
#define LDPV 68   // V^T rows: 136B (8B-aligned)

typedef __attribute__((ext_vector_type(4)))  float f32x4;
typedef __attribute__((ext_vector_type(16))) float f32x16;
typedef __attribute__((ext_vector_type(8)))  short short8v;
typedef __attribute__((ext_vector_type(4)))  unsigned uint4v;
typedef __attribute__((ext_vector_type(2)))  unsigned uint2v;

__device__ __forceinline__ unsigned cvt_pk(float a, float b) {
    unsigned r;
    asm("v_cvt_pk_bf16_f32 %0, %1, %2" : "=v"(r) : "v"(a), "v"(b));
    return r;
}

__global__ __launch_bounds__(256) void fa_fwd_kernel(
    const float* __restrict__ Q, const float* __restrict__ K,
    const float* __restrict__ V, float* __restrict__ O)
{
    const int tid  = threadIdx.x;
    const int lane = tid & 63;
    const int w    = tid >> 6;          // 0..3 waves, each owns 32 q-rows (one 32x32 col-tile)
    const int bh   = blockIdx.x & 63;   // same-bh blocks 64 apart -> same XCD
    const int p    = blockIdx.x >> 6;   // sequential pair {15-p, p}: 34 iters uniform

    const size_t base = (size_t)bh * S_LEN * DH;
    const float* Qg = Q + base;
    const float* Kg = K + base;
    const float* Vg = V + base;
    float*       Og = O + base;

    __shared__ __align__(16) short K_lds[2][KVBLK][LDPK];   // [buf][kv][d]
    __shared__ __align__(16) short V_lds[2][DH][LDPV];      // [buf][d][kv]

    const int q  = lane & 31;           // this lane's q-column within the wave tile
    const int hi = lane >> 5;           // 0/1: k-slot half
    // staging decomposition (256 threads cover the 64x64 tile once)
    const int kr = tid >> 2;            // K row 0..63
    const int dc = (tid & 3) * 16;      // K col 0,16,32,48
    const int vd = tid & 63;            // V col (d)
    const int vg = tid >> 6;            // V row-group 0..3

    unsigned kpfu[8], vpf[8];

    auto prefetch = [&](int kvb) {
        const float* kp = Kg + (size_t)(kvb + kr) * DH + dc;
        f32x4 a = *(const f32x4*)kp;
        f32x4 b = *(const f32x4*)(kp + 4);
        f32x4 c = *(const f32x4*)(kp + 8);
        f32x4 d = *(const f32x4*)(kp + 12);
        kpfu[0] = cvt_pk(a[0], a[1]); kpfu[1] = cvt_pk(a[2], a[3]);
        kpfu[2] = cvt_pk(b[0], b[1]); kpfu[3] = cvt_pk(b[2], b[3]);
        kpfu[4] = cvt_pk(c[0], c[1]); kpfu[5] = cvt_pk(c[2], c[3]);
        kpfu[6] = cvt_pk(d[0], d[1]); kpfu[7] = cvt_pk(d[2], d[3]);
        #pragma unroll
        for (int i = 0; i < 8; ++i) {
            int kv = vg * 16 + i * 2;
            float x = Vg[(size_t)(kvb + kv) * DH + vd];
            float y = Vg[(size_t)(kvb + kv + 1) * DH + vd];
            vpf[i] = cvt_pk(x, y);
        }
    };

    auto stage = [&](int b) {
        uint4v u0 = {kpfu[0], kpfu[1], kpfu[2], kpfu[3]};
        uint4v u1 = {kpfu[4], kpfu[5], kpfu[6], kpfu[7]};
        *(uint4v*)&K_lds[b][kr][dc]     = u0;   // ds_write_b128
        *(uint4v*)&K_lds[b][kr][dc + 8] = u1;
        #pragma unroll
        for (int i = 0; i < 8; ++i) {
            int kv = vg * 16 + i * 2;
            *(unsigned*)((char*)&V_lds[b][0][0] + vd * (LDPV * 2) + kv * 2) = vpf[i];
        }
    };

    const float qscale = 0.125f * 1.44269504088896340736f;

    prefetch(0);
    stage(0);
    int cur = 0;
    __syncthreads();

    #pragma unroll 1
    for (int t = 0; t < 2; ++t) {
        const int qb = (t == 0) ? (15 - p) : p;   // heavy tile first
        const int q0 = qb * QBLK + w * 32;        // wave's first q-row
        const int kv_end = (qb + 1) * QBLK;

        // ---- Q B-fragments: lane supplies Q[d = ds*16 + hi*8 + j][q0+q], scaled ----
        short8v qfrag[4];
        #pragma unroll
        for (int ds = 0; ds < 4; ++ds) {
            const float* qp = Qg + (size_t)(q0 + q) * DH + ds * 16 + hi * 8;
            f32x4 a = *(const f32x4*)qp;
            f32x4 b = *(const f32x4*)(qp + 4);
            uint4v u;
            u[0] = cvt_pk(a[0] * qscale, a[1] * qscale);
            u[1] = cvt_pk(a[2] * qscale, a[3] * qscale);
            u[2] = cvt_pk(b[0] * qscale, b[1] * qscale);
            u[3] = cvt_pk(b[2] * qscale, b[3] * qscale);
            qfrag[ds] = __builtin_bit_cast(short8v, u);
        }

        f32x16 o_acc[2];   // O^T[dt*32 + rowmap][q]
        o_acc[0] = (f32x16)(0.f);
        o_acc[1] = (f32x16)(0.f);
        float m_run = -1e30f, l_run = 0.f;

        #pragma unroll 1
        for (int kvb = 0; kvb < kv_end; kvb += KVBLK) {
            int nkv = kvb + KVBLK;
            bool have = true;
            if (nkv >= kv_end) { if (t == 0) nkv = 0; else have = false; }
            if (have) prefetch(nkv);   // global->reg, lands under compute

            if (kvb <= q0) {           // skip fully-masked diagonal iterations
                const short (*Kc)[LDPK] = K_lds[cur];
                const char* Vc = (const char*)&V_lds[cur][0][0];

                // ---- swapped QK^T: S^T[kv][q] = K·Q^T, two 32-kv tiles ----
                f32x16 s_acc[2];
                s_acc[0] = (f32x16)(0.f);
                s_acc[1] = (f32x16)(0.f);

                __builtin_amdgcn_s_setprio(1);
                #pragma unroll
                for (int ds = 0; ds < 4; ++ds) {
                    #pragma unroll
                    for (int kt = 0; kt < 2; ++kt) {
                        short8v kf = *(const short8v*)&Kc[kt * 32 + q][ds * 16 + hi * 8];
                        s_acc[kt] = __builtin_amdgcn_mfma_f32_32x32x16_bf16(
                            kf, qfrag[ds], s_acc[kt], 0, 0, 0);
                    }
                }
                __builtin_amdgcn_s_setprio(0);

                // ---- mask (diagonal tiles only): kv = kvb+32kt+(r&3)+8(r>>2)+4hi ----
                const int qrow = q0 + q;
                if (kvb + KVBLK - 1 > q0) {
                    #pragma unroll
                    for (int kt = 0; kt < 2; ++kt)
                        #pragma unroll
                        for (int r = 0; r < 16; ++r) {
                            int kv = kvb + kt * 32 + (r & 3) + 8 * (r >> 2) + 4 * hi;
                            if (kv > qrow) s_acc[kt][r] = -1e30f;
                        }
                }

                // ---- softmax: fully in-lane except ONE shfl_xor(32) each ----
                float tl = -1e30f;
                #pragma unroll
                for (int kt = 0; kt < 2; ++kt)
                    #pragma unroll
                    for (int r = 0; r < 16; ++r)
                        tl = fmaxf(tl, s_acc[kt][r]);
                float tmax = fmaxf(tl, __shfl_xor(tl, 32));

                if (!__all(tmax <= m_run + 8.0f)) {
                    float mnew = fmaxf(m_run, tmax);
                    float corr = __builtin_amdgcn_exp2f(m_run - mnew);
                    m_run = mnew;
                    l_run *= corr;
                    #pragma unroll
                    for (int dt = 0; dt < 2; ++dt)
                        #pragma unroll
                        for (int r = 0; r < 16; ++r)
                            o_acc[dt][r] *= corr;   // in-lane: o col == this lane's q
                }

                float rsum = 0.f;
                #pragma unroll
                for (int kt = 0; kt < 2; ++kt)
                    #pragma unroll
                    for (int r = 0; r < 16; ++r) {
                        float pe = __builtin_amdgcn_exp2f(s_acc[kt][r] - m_run);
                        s_acc[kt][r] = pe;
                        rsum += pe;
                    }
                rsum += __shfl_xor(rsum, 32);
                l_run += rsum;

                // ---- pack P to bf16; registers land directly in B-frag k-slot order ----
                unsigned pk_[2][8];
                #pragma unroll
                for (int kt = 0; kt < 2; ++kt)
                    #pragma unroll
                    for (int m = 0; m < 8; ++m)
                        pk_[kt][m] = cvt_pk(s_acc[kt][2 * m], s_acc[kt][2 * m + 1]);

                // ---- PV: O^T += V^T · P ; A-frag k-order kv = 16s + (j&3)+8(j>>2)+4hi ----
                __builtin_amdgcn_s_setprio(1);
                #pragma unroll
                for (int s = 0; s < 4; ++s) {
                    const int kt = s >> 1, bofs = 4 * (s & 1);
                    uint4v bu = {pk_[kt][bofs], pk_[kt][bofs + 1],
                                 pk_[kt][bofs + 2], pk_[kt][bofs + 3]};
                    short8v pb = __builtin_bit_cast(short8v, bu);
                    #pragma unroll
                    for (int dt = 0; dt < 2; ++dt) {
                        const char* vrow = Vc + (size_t)(dt * 32 + q) * (LDPV * 2);
                        uint2v lo = *(const uint2v*)(vrow + (16 * s + 4 * hi) * 2);
                        uint2v h2 = *(const uint2v*)(vrow + (16 * s + 8 + 4 * hi) * 2);
                        uint4v au = {lo[0], lo[1], h2[0], h2[1]};
                        short8v va = __builtin_bit_cast(short8v, au);
                        o_acc[dt] = __builtin_amdgcn_mfma_f32_32x32x16_bf16(
                            va, pb, o_acc[dt], 0, 0, 0);
                    }
                }
                __builtin_amdgcn_s_setprio(0);
            }

            if (have) {
                stage(cur ^ 1);
                __syncthreads();
            }
            cur ^= 1;
        }

        // ---- epilogue: all in-lane; O[q][d], d = dt*32 + 8g + 4hi + i ----
        float inv = 1.0f / l_run;
        float* orow = Og + (size_t)(q0 + q) * DH;
        #pragma unroll
        for (int dt = 0; dt < 2; ++dt) {
            #pragma unroll
            for (int g = 0; g < 4; ++g) {
                f32x4 ov = {o_acc[dt][4 * g] * inv,     o_acc[dt][4 * g + 1] * inv,
                            o_acc[dt][4 * g + 2] * inv, o_acc[dt][4 * g + 3] * inv};
                *(f32x4*)(orow + dt * 32 + 8 * g + 4 * hi) = ov;
            }
        }
    }
}

extern "C" void kernel_launch(void* const* d_in, const int* in_sizes, int n_in,
                              void* d_out, int out_size, void* d_ws, size_t ws_size,
                              hipStream_t stream) {
    const float* q = (const float*)d_in[0];
    const float* k = (const float*)d_in[1];
    const float* v = (const float*)d_in[2];
    float* out = (float*)d_out;
    // 512 uniform blocks x 256 threads: 64 (b,h) x 8 q-tile pairs {15-p, p}, 32x32 MFMA
    fa_fwd_kernel<<<dim3(512), dim3(256), 0, stream>>>(q, k, v, out);
}

// Round 10
// 65.680 us; speedup vs baseline: 2.3684x; 1.3240x over previous
//
#include <hip/hip_runtime.h>
#include <hip/hip_bf16.h>

#define S_LEN 2048
#define DH 64
#define QBLK 128
#define KVBLK 64
#define LDPK 72   // K rows: 144B (16B-aligned)
#define LDPV 68   // V^T rows: 136B (8B-aligned)

typedef __attribute__((ext_vector_type(4)))  float f32x4;
typedef __attribute__((ext_vector_type(16))) float f32x16;
typedef __attribute__((ext_vector_type(8)))  short short8v;
typedef __attribute__((ext_vector_type(4)))  unsigned uint4v;
typedef __attribute__((ext_vector_type(2)))  unsigned uint2v;

__device__ __forceinline__ unsigned cvt_pk(float a, float b) {
    unsigned r;
    asm("v_cvt_pk_bf16_f32 %0, %1, %2" : "=v"(r) : "v"(a), "v"(b));
    return r;
}

__global__ __launch_bounds__(512) void fa_fwd_kernel(
    const float* __restrict__ Q, const float* __restrict__ K,
    const float* __restrict__ V, float* __restrict__ O)
{
    const int tid  = threadIdx.x;
    const int lane = tid & 63;
    const int w    = tid >> 6;          // 0..7 waves
    const int bh   = blockIdx.x & 63;   // same-bh blocks 64 apart -> same XCD
    const int p    = blockIdx.x >> 6;   // 0..7

    // concurrent pair: waves 0-3 -> q-tile (15-p) [heavy], waves 4-7 -> q-tile p [light];
    // both ride ONE monotonic KV stream [0, (16-p)*128). Light waves turn producer-only
    // after their causal extent -> CU never drops below 8 active waves.
    const int qb = (w < 4) ? (15 - p) : p;
    const int q0 = qb * QBLK + (w & 3) * 32;      // wave's first q-row
    const int kv_end = (16 - p) * QBLK;           // stream extent (heavy tile's)

    const size_t base = (size_t)bh * S_LEN * DH;
    const float* Qg = Q + base;
    const float* Kg = K + base;
    const float* Vg = V + base;
    float*       Og = O + base;

    __shared__ __align__(16) short K_lds[2][KVBLK][LDPK];   // [buf][kv][d]
    __shared__ __align__(16) short V_lds[2][DH][LDPV];      // [buf][d][kv]

    const int q  = lane & 31;           // lane's q-column within the wave tile
    const int hi = lane >> 5;           // 0/1: k-slot half
    // staging decomposition (512 threads cover the 64x64 tile once)
    const int kr = tid >> 3;            // K row 0..63
    const int dc = (tid & 7) * 8;       // K col 0,8,...,56
    const int vd = tid & 63;            // V col (d)
    const int vg = tid >> 6;            // V row-group 0..7

    unsigned kpfu[4], vpf[4];

    auto prefetch = [&](int kvb) {
        const float* kp = Kg + (size_t)(kvb + kr) * DH + dc;
        f32x4 a = *(const f32x4*)kp;
        f32x4 b = *(const f32x4*)(kp + 4);
        kpfu[0] = cvt_pk(a[0], a[1]); kpfu[1] = cvt_pk(a[2], a[3]);
        kpfu[2] = cvt_pk(b[0], b[1]); kpfu[3] = cvt_pk(b[2], b[3]);
        #pragma unroll
        for (int i = 0; i < 4; ++i) {
            int kv = vg * 8 + i * 2;
            float x = Vg[(size_t)(kvb + kv) * DH + vd];
            float y = Vg[(size_t)(kvb + kv + 1) * DH + vd];
            vpf[i] = cvt_pk(x, y);
        }
    };

    auto stage = [&](int b) {
        uint4v u = {kpfu[0], kpfu[1], kpfu[2], kpfu[3]};
        *(uint4v*)&K_lds[b][kr][dc] = u;   // ds_write_b128
        #pragma unroll
        for (int i = 0; i < 4; ++i) {
            int kv = vg * 8 + i * 2;
            *(unsigned*)((char*)&V_lds[b][0][0] + vd * (LDPV * 2) + kv * 2) = vpf[i];
        }
    };

    const float qscale = 0.125f * 1.44269504088896340736f;

    // ---- Q B-fragments: lane supplies Q[d = ds*16 + hi*8 + j][q0+q], scaled ----
    short8v qfrag[4];
    #pragma unroll
    for (int ds = 0; ds < 4; ++ds) {
        const float* qp = Qg + (size_t)(q0 + q) * DH + ds * 16 + hi * 8;
        f32x4 a = *(const f32x4*)qp;
        f32x4 b = *(const f32x4*)(qp + 4);
        uint4v u;
        u[0] = cvt_pk(a[0] * qscale, a[1] * qscale);
        u[1] = cvt_pk(a[2] * qscale, a[3] * qscale);
        u[2] = cvt_pk(b[0] * qscale, b[1] * qscale);
        u[3] = cvt_pk(b[2] * qscale, b[3] * qscale);
        qfrag[ds] = __builtin_bit_cast(short8v, u);
    }

    f32x16 o_acc[2];   // O^T[dt*32 + rowmap][q]
    o_acc[0] = (f32x16)(0.f);
    o_acc[1] = (f32x16)(0.f);
    float m_run = -1e30f, l_run = 0.f;

    prefetch(0);
    stage(0);
    int cur = 0;
    __syncthreads();

    #pragma unroll 1
    for (int kvb = 0; kvb < kv_end; kvb += KVBLK) {
        int nkv = kvb + KVBLK;
        const bool have = nkv < kv_end;
        if (have) prefetch(nkv);   // global->reg, lands under compute

        if (kvb <= q0) {           // this wave still inside its causal extent
            const short (*Kc)[LDPK] = K_lds[cur];
            const char* Vc = (const char*)&V_lds[cur][0][0];

            // ---- swapped QK^T: S^T[kv][q] = K·Q^T, two 32-kv tiles ----
            f32x16 s_acc[2];
            s_acc[0] = (f32x16)(0.f);
            s_acc[1] = (f32x16)(0.f);

            __builtin_amdgcn_s_setprio(1);
            #pragma unroll
            for (int ds = 0; ds < 4; ++ds) {
                #pragma unroll
                for (int kt = 0; kt < 2; ++kt) {
                    short8v kf = *(const short8v*)&Kc[kt * 32 + q][ds * 16 + hi * 8];
                    s_acc[kt] = __builtin_amdgcn_mfma_f32_32x32x16_bf16(
                        kf, qfrag[ds], s_acc[kt], 0, 0, 0);
                }
            }
            __builtin_amdgcn_s_setprio(0);

            // ---- mask (diagonal tiles only): kv = kvb+32kt+(r&3)+8(r>>2)+4hi ----
            const int qrow = q0 + q;
            if (kvb + KVBLK - 1 > q0) {
                #pragma unroll
                for (int kt = 0; kt < 2; ++kt)
                    #pragma unroll
                    for (int r = 0; r < 16; ++r) {
                        int kv = kvb + kt * 32 + (r & 3) + 8 * (r >> 2) + 4 * hi;
                        if (kv > qrow) s_acc[kt][r] = -1e30f;
                    }
            }

            // ---- softmax: fully in-lane except ONE shfl_xor(32) each ----
            float tl = -1e30f;
            #pragma unroll
            for (int kt = 0; kt < 2; ++kt)
                #pragma unroll
                for (int r = 0; r < 16; ++r)
                    tl = fmaxf(tl, s_acc[kt][r]);
            float tmax = fmaxf(tl, __shfl_xor(tl, 32));

            if (!__all(tmax <= m_run + 8.0f)) {
                float mnew = fmaxf(m_run, tmax);
                float corr = __builtin_amdgcn_exp2f(m_run - mnew);
                m_run = mnew;
                l_run *= corr;
                #pragma unroll
                for (int dt = 0; dt < 2; ++dt)
                    #pragma unroll
                    for (int r = 0; r < 16; ++r)
                        o_acc[dt][r] *= corr;   // in-lane: o col == this lane's q
            }

            float rsum = 0.f;
            #pragma unroll
            for (int kt = 0; kt < 2; ++kt)
                #pragma unroll
                for (int r = 0; r < 16; ++r) {
                    float pe = __builtin_amdgcn_exp2f(s_acc[kt][r] - m_run);
                    s_acc[kt][r] = pe;
                    rsum += pe;
                }
            rsum += __shfl_xor(rsum, 32);
            l_run += rsum;

            // ---- pack P to bf16; registers land directly in B-frag k-slot order ----
            unsigned pk_[2][8];
            #pragma unroll
            for (int kt = 0; kt < 2; ++kt)
                #pragma unroll
                for (int m = 0; m < 8; ++m)
                    pk_[kt][m] = cvt_pk(s_acc[kt][2 * m], s_acc[kt][2 * m + 1]);

            // ---- PV: O^T += V^T · P ; A-frag k-order kv = 16s + (j&3)+8(j>>2)+4hi ----
            __builtin_amdgcn_s_setprio(1);
            #pragma unroll
            for (int s = 0; s < 4; ++s) {
                const int kt = s >> 1, bofs = 4 * (s & 1);
                uint4v bu = {pk_[kt][bofs], pk_[kt][bofs + 1],
                             pk_[kt][bofs + 2], pk_[kt][bofs + 3]};
                short8v pb = __builtin_bit_cast(short8v, bu);
                #pragma unroll
                for (int dt = 0; dt < 2; ++dt) {
                    const char* vrow = Vc + (size_t)(dt * 32 + q) * (LDPV * 2);
                    uint2v lo = *(const uint2v*)(vrow + (16 * s + 4 * hi) * 2);
                    uint2v h2 = *(const uint2v*)(vrow + (16 * s + 8 + 4 * hi) * 2);
                    uint4v au = {lo[0], lo[1], h2[0], h2[1]};
                    short8v va = __builtin_bit_cast(short8v, au);
                    o_acc[dt] = __builtin_amdgcn_mfma_f32_32x32x16_bf16(
                        va, pb, o_acc[dt], 0, 0, 0);
                }
            }
            __builtin_amdgcn_s_setprio(0);
        }

        if (have) {
            stage(cur ^ 1);
            __syncthreads();
        }
        cur ^= 1;
    }

    // ---- epilogue: all in-lane; O[q][d], d = dt*32 + 8g + 4hi + i ----
    float inv = 1.0f / l_run;
    float* orow = Og + (size_t)(q0 + q) * DH;
    #pragma unroll
    for (int dt = 0; dt < 2; ++dt) {
        #pragma unroll
        for (int g = 0; g < 4; ++g) {
            f32x4 ov = {o_acc[dt][4 * g] * inv,     o_acc[dt][4 * g + 1] * inv,
                        o_acc[dt][4 * g + 2] * inv, o_acc[dt][4 * g + 3] * inv};
            *(f32x4*)(orow + dt * 32 + 8 * g + 4 * hi) = ov;
        }
    }
}

extern "C" void kernel_launch(void* const* d_in, const int* in_sizes, int n_in,
                              void* d_out, int out_size, void* d_ws, size_t ws_size,
                              hipStream_t stream) {
    const float* q = (const float*)d_in[0];
    const float* k = (const float*)d_in[1];
    const float* v = (const float*)d_in[2];
    float* out = (float*)d_out;
    // 512 blocks x 512 threads: 64 (b,h) x 8 concurrent pairs {15-p, p}; 16 waves/CU
    fa_fwd_kernel<<<dim3(512), dim3(512), 0, stream>>>(q, k, v, out);
}